// Round 4
// baseline (192.073 us; speedup 1.0000x reference)
//
#include <hip/hip_runtime.h>

#define T_OUT 18
#define NAG   20000
#define EMBD  64
#define HIDD  128
#define APB   80      // agents per block; 250 * 80 = 20000 exactly
#define SH    136     // h LDS row stride in halves
#define SE    72      // emb LDS row stride in halves

typedef _Float16 half8 __attribute__((ext_vector_type(8)));
typedef float    f32x4 __attribute__((ext_vector_type(4)));

__device__ __forceinline__ float rcpf(float x) { return __builtin_amdgcn_rcpf(x); }
__device__ __forceinline__ float sigmf(float x) { return rcpf(1.0f + __expf(-x)); }

__global__
__attribute__((amdgpu_flat_work_group_size(512, 512), amdgpu_waves_per_eu(2, 2)))
void lstm_seq_kernel(
    const float* __restrict__ obs,
    const float* __restrict__ w_emb,  const float* __restrict__ b_emb,
    const float* __restrict__ w_ih_e, const float* __restrict__ b_ih_e,
    const float* __restrict__ w_hh_e, const float* __restrict__ b_hh_e,
    const float* __restrict__ w_ih_d, const float* __restrict__ b_ih_d,
    const float* __restrict__ w_hh_d, const float* __restrict__ b_hh_d,
    const float* __restrict__ w_out,  const float* __restrict__ b_out,
    float* __restrict__ out)
{
  __shared__ __align__(16) _Float16 h_s[2][APB * SH];   // double-buffered hidden state
  __shared__ __align__(16) _Float16 e_s[APB * SE];
  __shared__ float vel_s[APB * 2];
  __shared__ float mask_s[2][APB];

  const int tid = threadIdx.x;
  const int wv  = tid >> 6;
  const int ln  = tid & 63;
  const int l15 = ln & 15;
  const int lg  = ln >> 4;
  const int a0  = blockIdx.x * APB;
  const int po  = tid - 320;                       // obs-owner lanes: waves 5..6
  const bool obsOwner = ((unsigned)po) < APB;

  for (int i = tid; i < APB * SH; i += 512) h_s[0][i] = (_Float16)0.f;

  const float we0 = 4.f * w_emb[ln * 2 + 0];
  const float we1 = 4.f * w_emb[ln * 2 + 1];
  const float be  = b_emb[ln];

  // obs prologue: vel/mask for t=0; keep o2 in regs
  float o2x = 0.f, o2y = 0.f;
  if (obsOwner) {
    int a = a0 + po;
    float o1x = obs[(0 * NAG + a) * 2 + 0];
    float o2x_ = obs[(1 * NAG + a) * 2 + 0], o2y_ = obs[(1 * NAG + a) * 2 + 1];
    float o1y = obs[(0 * NAG + a) * 2 + 1];
    bool ok = !__builtin_isnan(o1x) && !__builtin_isnan(o2x_);
    mask_s[0][po] = ok ? 1.f : 0.f;
    vel_s[po * 2 + 0] = ok ? (o2x_ - o1x) : 0.f;
    vel_s[po * 2 + 1] = ok ? (o2y_ - o1y) : 0.f;
    o2x = o2x_; o2y = o2y_;
  }

  // ---- weight fragments ----
  half8 fih[4][2];
  half8 fhh[4][4];
  half8 fout[4];
  float bsum[4], bo;

  {
    int j = l15;
    #pragma unroll
    for (int ks = 0; ks < 4; ks++) {
      half8 v;
      #pragma unroll
      for (int q = 0; q < 8; q++) {
        float x = (j < 5) ? w_out[j * HIDD + ks * 32 + lg * 8 + q] : 0.f;
        v[q] = (_Float16)x;
      }
      fout[ks] = v;
    }
    bo = (j < 5) ? b_out[j] : 0.f;
  }

  auto load_phase = [&](const float* wih, const float* bih,
                        const float* whh, const float* bhh) {
    #pragma unroll
    for (int n = 0; n < 4; n++) {
      int row = n * 128 + wv * 16 + l15;
      #pragma unroll
      for (int ks = 0; ks < 2; ks++) {
        const float* p = wih + row * EMBD + ks * 32 + lg * 8;
        half8 v;
        #pragma unroll
        for (int q = 0; q < 8; q++) v[q] = (_Float16)p[q];
        fih[n][ks] = v;
      }
      #pragma unroll
      for (int ks = 0; ks < 4; ks++) {
        const float* p = whh + row * HIDD + ks * 32 + lg * 8;
        half8 v;
        #pragma unroll
        for (int q = 0; q < 8; q++) v[q] = (_Float16)p[q];
        fhh[n][ks] = v;
      }
      bsum[n] = bih[row] + bhh[row];
    }
  };

  auto emb_compute = [&]() {
    #pragma unroll
    for (int k = 0; k < 10; k++) {
      int a = wv + 8 * k;
      float vx = vel_s[a * 2], vy = vel_s[a * 2 + 1];
      float e = fmaf(vx, we0, fmaf(vy, we1, be));
      e_s[a * SE + ln] = (_Float16)fmaxf(e, 0.f);
    }
  };

  load_phase(w_ih_e, b_ih_e, w_hh_e, b_hh_e);
  __syncthreads();
  emb_compute();          // emb for t=0
  __syncthreads();

  float c_r[5][4];   // cell state, lane-local (f32)
  float h_r[5][4];   // this lane's copy of its h cells (rounded to f16)
  #pragma unroll
  for (int m = 0; m < 5; m++)
    #pragma unroll
    for (int r = 0; r < 4; r++) { c_r[m][r] = 0.f; h_r[m][r] = 0.f; }

  const int hid = wv * 16 + l15;

  #pragma unroll 1
  for (int t = 0; t < T_OUT; t++) {
    if (t == 8) load_phase(w_ih_d, b_ih_d, w_hh_d, b_hh_d);

    const int idx  = t & 1;
    const int nidx = idx ^ 1;

    // issue obs loads for t+2 (consumed after the m-loop)
    float n2x = 0.f, n2y = 0.f;
    if (t + 1 < T_OUT && obsOwner) {
      int a = a0 + po;
      n2x = obs[((size_t)(t + 2) * NAG + a) * 2 + 0];
      n2y = obs[((size_t)(t + 2) * NAG + a) * 2 + 1];
    }

    // ---- phase A: per 16-agent group: gate MFMAs + elementwise + h write ----
    #pragma unroll 1
    for (int m = 0; m < 5; m++) {
      f32x4 acc[4];
      #pragma unroll
      for (int n = 0; n < 4; n++)
        acc[n] = f32x4{bsum[n], bsum[n], bsum[n], bsum[n]};

      #pragma unroll
      for (int ks = 0; ks < 2; ks++) {
        half8 av = *(const half8*)&e_s[(m * 16 + l15) * SE + ks * 32 + lg * 8];
        #pragma unroll
        for (int n = 0; n < 4; n++)
          acc[n] = __builtin_amdgcn_mfma_f32_16x16x32_f16(av, fih[n][ks], acc[n], 0, 0, 0);
      }
      #pragma unroll
      for (int ks = 0; ks < 4; ks++) {
        half8 av = *(const half8*)&h_s[idx][(m * 16 + l15) * SH + ks * 32 + lg * 8];
        #pragma unroll
        for (int n = 0; n < 4; n++)
          acc[n] = __builtin_amdgcn_mfma_f32_16x16x32_f16(av, fhh[n][ks], acc[n], 0, 0, 0);
      }

      // elementwise LSTM for this lane's 4 cells (paired rcp)
      float c2a[4], ova[4];
      #pragma unroll
      for (int r = 0; r < 4; r++) {
        float ai = acc[0][r], af = acc[1][r];
        float ag_ = acc[2][r], ao = acc[3][r];
        float ei = __expf(-ai), ef = __expf(-af);
        float eo = __expf(-ao), eg = __expf(-2.f * ag_);
        float di = 1.f + ei, df = 1.f + ef, dd = 1.f + eo, dg = 1.f + eg;
        float p1 = rcpf(di * df);
        float iv = df * p1, fv = di * p1;
        float p2 = rcpf(dd * dg);
        float ov = dg * p2;
        float gv = fmaf(2.f, dd * p2, -1.f);
        c2a[r] = fmaf(fv, c_r[m][r], iv * gv);
        ova[r] = ov;
      }
      float dc[4];
      #pragma unroll
      for (int r = 0; r < 4; r++) dc[r] = 1.f + __expf(-2.f * c2a[r]);
      float q01 = rcpf(dc[0] * dc[1]);
      float q23 = rcpf(dc[2] * dc[3]);
      float inv[4] = { dc[1] * q01, dc[0] * q01, dc[3] * q23, dc[2] * q23 };
      #pragma unroll
      for (int r = 0; r < 4; r++) {
        int ag = m * 16 + lg * 4 + r;
        float mk = mask_s[idx][ag];
        float th = fmaf(2.f, inv[r], -1.f);
        float h2 = ova[r] * th;
        bool on = (mk != 0.f);
        c_r[m][r] = on ? c2a[r] : c_r[m][r];
        _Float16 hh = (_Float16)(on ? h2 : h_r[m][r]);
        h_s[nidx][ag * SH + hid] = hh;
        h_r[m][r] = (float)hh;
      }
    }

    // vel/mask for t+1 (consume prefetched obs)
    if (t + 1 < T_OUT && obsOwner) {
      float n1x = o2x, n1y = o2y;
      bool ok = !__builtin_isnan(n1x) && !__builtin_isnan(n2x);
      mask_s[nidx][po] = ok ? 1.f : 0.f;
      vel_s[po * 2 + 0] = ok ? (n2x - n1x) : 0.f;
      vel_s[po * 2 + 1] = ok ? (n2y - n1y) : 0.f;
      o2x = n2x; o2y = n2y;
    }
    __syncthreads();   // bar1: h_{t+1} complete; A-reads of e_s done; vel/mask published

    // ---- phase B: output head for step t (reads h_{t+1}) + emb for t+1 ----
    if (wv < 5) {
      f32x4 oa = f32x4{bo, bo, bo, bo};
      #pragma unroll
      for (int ks = 0; ks < 4; ks++) {
        half8 av = *(const half8*)&h_s[nidx][(wv * 16 + l15) * SH + ks * 32 + lg * 8];
        oa = __builtin_amdgcn_mfma_f32_16x16x32_f16(av, fout[ks], oa, 0, 0, 0);
      }
      int j = l15;
      #pragma unroll
      for (int r = 0; r < 4; r++) {
        int ag = wv * 16 + lg * 4 + r;
        float mk = mask_s[idx][ag];
        float nv = oa[r];
        float y;
        if (j < 2)      y = nv;
        else if (j < 4) y = 0.01f + 0.2f * sigmf(nv);
        else            y = 0.7f * sigmf(nv);
        if (j < 5) out[((size_t)t * NAG + a0 + ag) * 5 + j] = y * mk;
      }
    }
    if (t + 1 < T_OUT) emb_compute();
    __syncthreads();   // bar2: e_{t+1} visible before next step's MFMAs
  }
}

extern "C" void kernel_launch(void* const* d_in, const int* in_sizes, int n_in,
                              void* d_out, int out_size, void* d_ws, size_t ws_size,
                              hipStream_t stream) {
  const float* obs    = (const float*)d_in[0];
  const float* w_emb  = (const float*)d_in[2];
  const float* b_emb  = (const float*)d_in[3];
  const float* w_ih_e = (const float*)d_in[4];
  const float* b_ih_e = (const float*)d_in[5];
  const float* w_hh_e = (const float*)d_in[6];
  const float* b_hh_e = (const float*)d_in[7];
  const float* w_ih_d = (const float*)d_in[8];
  const float* b_ih_d = (const float*)d_in[9];
  const float* w_hh_d = (const float*)d_in[10];
  const float* b_hh_d = (const float*)d_in[11];
  const float* w_out  = (const float*)d_in[12];
  const float* b_out  = (const float*)d_in[13];
  float* out = (float*)d_out;

  lstm_seq_kernel<<<dim3(250), dim3(512), 0, stream>>>(
      obs, w_emb, b_emb, w_ih_e, b_ih_e, w_hh_e, b_hh_e,
      w_ih_d, b_ih_d, w_hh_d, b_hh_d, w_out, b_out, out);
}

// Round 5
// 131.601 us; speedup vs baseline: 1.4595x; 1.4595x over previous
//
#include <hip/hip_runtime.h>

#define T_OUT 18
#define NAG   20000
#define EMBD  64
#define HIDD  128
#define APB   80      // agents per block; 250 * 80 = 20000 exactly
#define SH    136     // h LDS row stride in halves
#define SE    72      // emb LDS row stride in halves

typedef _Float16 half8 __attribute__((ext_vector_type(8)));
typedef float    f32x4 __attribute__((ext_vector_type(4)));

__device__ __forceinline__ float rcpf(float x) { return __builtin_amdgcn_rcpf(x); }
__device__ __forceinline__ float sigmf(float x) { return rcpf(1.0f + __expf(-x)); }

__global__
__attribute__((amdgpu_flat_work_group_size(512, 512), amdgpu_waves_per_eu(2, 2)))
void lstm_seq_kernel(
    const float* __restrict__ obs,
    const float* __restrict__ w_emb,  const float* __restrict__ b_emb,
    const float* __restrict__ w_ih_e, const float* __restrict__ b_ih_e,
    const float* __restrict__ w_hh_e, const float* __restrict__ b_hh_e,
    const float* __restrict__ w_ih_d, const float* __restrict__ b_ih_d,
    const float* __restrict__ w_hh_d, const float* __restrict__ b_hh_d,
    const float* __restrict__ w_out,  const float* __restrict__ b_out,
    float* __restrict__ out)
{
  __shared__ __align__(16) _Float16 h_s[2][APB * SH];   // double-buffered hidden state
  __shared__ __align__(16) _Float16 e_s[APB * SE];
  __shared__ float vel_s[APB * 2];
  __shared__ float mask_s[2][APB];

  const int tid = threadIdx.x;
  const int wv  = tid >> 6;
  const int ln  = tid & 63;
  const int l15 = ln & 15;
  const int lg  = ln >> 4;
  const int a0  = blockIdx.x * APB;
  const int po  = tid - 320;                       // obs-owner lanes: waves 5..6
  const bool obsOwner = ((unsigned)po) < APB;

  for (int i = tid; i < APB * SH; i += 512) h_s[0][i] = (_Float16)0.f;

  const float we0 = 4.f * w_emb[ln * 2 + 0];
  const float we1 = 4.f * w_emb[ln * 2 + 1];
  const float be  = b_emb[ln];

  // obs prologue: vel/mask for t=0; keep o2 in regs
  float o2x = 0.f, o2y = 0.f;
  if (obsOwner) {
    int a = a0 + po;
    float o1x = obs[(0 * NAG + a) * 2 + 0];
    float o2x_ = obs[(1 * NAG + a) * 2 + 0], o2y_ = obs[(1 * NAG + a) * 2 + 1];
    float o1y = obs[(0 * NAG + a) * 2 + 1];
    bool ok = !__builtin_isnan(o1x) && !__builtin_isnan(o2x_);
    mask_s[0][po] = ok ? 1.f : 0.f;
    vel_s[po * 2 + 0] = ok ? (o2x_ - o1x) : 0.f;
    vel_s[po * 2 + 1] = ok ? (o2y_ - o1y) : 0.f;
    o2x = o2x_; o2y = o2y_;
  }

  // ---- weight fragments ----
  half8 fih[4][2];
  half8 fhh[4][4];
  half8 fout[4];
  float bsum[4], bo;

  {
    int j = l15;
    #pragma unroll
    for (int ks = 0; ks < 4; ks++) {
      half8 v;
      #pragma unroll
      for (int q = 0; q < 8; q++) {
        float x = (j < 5) ? w_out[j * HIDD + ks * 32 + lg * 8 + q] : 0.f;
        v[q] = (_Float16)x;
      }
      fout[ks] = v;
    }
    bo = (j < 5) ? b_out[j] : 0.f;
  }

  auto load_phase = [&](const float* wih, const float* bih,
                        const float* whh, const float* bhh) {
    #pragma unroll
    for (int n = 0; n < 4; n++) {
      int row = n * 128 + wv * 16 + l15;
      #pragma unroll
      for (int ks = 0; ks < 2; ks++) {
        const float* p = wih + row * EMBD + ks * 32 + lg * 8;
        half8 v;
        #pragma unroll
        for (int q = 0; q < 8; q++) v[q] = (_Float16)p[q];
        fih[n][ks] = v;
      }
      #pragma unroll
      for (int ks = 0; ks < 4; ks++) {
        const float* p = whh + row * HIDD + ks * 32 + lg * 8;
        half8 v;
        #pragma unroll
        for (int q = 0; q < 8; q++) v[q] = (_Float16)p[q];
        fhh[n][ks] = v;
      }
      bsum[n] = bih[row] + bhh[row];
    }
  };

  auto emb_compute = [&]() {
    #pragma unroll
    for (int k = 0; k < 10; k++) {
      int a = wv + 8 * k;
      float vx = vel_s[a * 2], vy = vel_s[a * 2 + 1];
      float e = fmaf(vx, we0, fmaf(vy, we1, be));
      e_s[a * SE + ln] = (_Float16)fmaxf(e, 0.f);
    }
  };

  load_phase(w_ih_e, b_ih_e, w_hh_e, b_hh_e);
  __syncthreads();
  emb_compute();          // emb for t=0
  __syncthreads();

  float c_r[5][4];   // cell state, lane-local (f32) — STATIC indexing only
  float h_r[5][4];   // this lane's copy of its h cells (rounded to f16)
  #pragma unroll
  for (int m = 0; m < 5; m++)
    #pragma unroll
    for (int r = 0; r < 4; r++) { c_r[m][r] = 0.f; h_r[m][r] = 0.f; }

  const int hid = wv * 16 + l15;

  #pragma unroll 1
  for (int t = 0; t < T_OUT; t++) {
    if (t == 8) load_phase(w_ih_d, b_ih_d, w_hh_d, b_hh_d);

    const int idx  = t & 1;
    const int nidx = idx ^ 1;

    // issue obs loads for t+2 (consumed after the m-loop)
    float n2x = 0.f, n2y = 0.f;
    if (t + 1 < T_OUT && obsOwner) {
      int a = a0 + po;
      n2x = obs[((size_t)(t + 2) * NAG + a) * 2 + 0];
      n2y = obs[((size_t)(t + 2) * NAG + a) * 2 + 1];
    }

    // ---- phase A: per 16-agent group: gate MFMAs + elementwise + h write ----
    // FULLY UNROLLED so c_r/h_r keep static indices (registers, not scratch)
    #pragma unroll
    for (int m = 0; m < 5; m++) {
      f32x4 acc[4];
      #pragma unroll
      for (int n = 0; n < 4; n++)
        acc[n] = f32x4{bsum[n], bsum[n], bsum[n], bsum[n]};

      #pragma unroll
      for (int ks = 0; ks < 2; ks++) {
        half8 av = *(const half8*)&e_s[(m * 16 + l15) * SE + ks * 32 + lg * 8];
        #pragma unroll
        for (int n = 0; n < 4; n++)
          acc[n] = __builtin_amdgcn_mfma_f32_16x16x32_f16(av, fih[n][ks], acc[n], 0, 0, 0);
      }
      #pragma unroll
      for (int ks = 0; ks < 4; ks++) {
        half8 av = *(const half8*)&h_s[idx][(m * 16 + l15) * SH + ks * 32 + lg * 8];
        #pragma unroll
        for (int n = 0; n < 4; n++)
          acc[n] = __builtin_amdgcn_mfma_f32_16x16x32_f16(av, fhh[n][ks], acc[n], 0, 0, 0);
      }

      // elementwise LSTM for this lane's 4 cells (paired rcp)
      float c2a[4], ova[4];
      #pragma unroll
      for (int r = 0; r < 4; r++) {
        float ai = acc[0][r], af = acc[1][r];
        float ag_ = acc[2][r], ao = acc[3][r];
        float ei = __expf(-ai), ef = __expf(-af);
        float eo = __expf(-ao), eg = __expf(-2.f * ag_);
        float di = 1.f + ei, df = 1.f + ef, dd = 1.f + eo, dg = 1.f + eg;
        float p1 = rcpf(di * df);
        float iv = df * p1, fv = di * p1;
        float p2 = rcpf(dd * dg);
        float ov = dg * p2;
        float gv = fmaf(2.f, dd * p2, -1.f);
        c2a[r] = fmaf(fv, c_r[m][r], iv * gv);
        ova[r] = ov;
      }
      float dc[4];
      #pragma unroll
      for (int r = 0; r < 4; r++) dc[r] = 1.f + __expf(-2.f * c2a[r]);
      float q01 = rcpf(dc[0] * dc[1]);
      float q23 = rcpf(dc[2] * dc[3]);
      float inv[4] = { dc[1] * q01, dc[0] * q01, dc[3] * q23, dc[2] * q23 };
      #pragma unroll
      for (int r = 0; r < 4; r++) {
        int ag = m * 16 + lg * 4 + r;
        float mk = mask_s[idx][ag];
        float th = fmaf(2.f, inv[r], -1.f);
        float h2 = ova[r] * th;
        bool on = (mk != 0.f);
        c_r[m][r] = on ? c2a[r] : c_r[m][r];
        _Float16 hh = (_Float16)(on ? h2 : h_r[m][r]);
        h_s[nidx][ag * SH + hid] = hh;
        h_r[m][r] = (float)hh;
      }
    }

    // vel/mask for t+1 (consume prefetched obs)
    if (t + 1 < T_OUT && obsOwner) {
      float n1x = o2x, n1y = o2y;
      bool ok = !__builtin_isnan(n1x) && !__builtin_isnan(n2x);
      mask_s[nidx][po] = ok ? 1.f : 0.f;
      vel_s[po * 2 + 0] = ok ? (n2x - n1x) : 0.f;
      vel_s[po * 2 + 1] = ok ? (n2y - n1y) : 0.f;
      o2x = n2x; o2y = n2y;
    }
    __syncthreads();   // bar1: h_{t+1} complete; A-reads of e_s done; vel/mask published

    // ---- phase B: output head for step t (reads h_{t+1}) + emb for t+1 ----
    if (wv < 5) {
      f32x4 oa = f32x4{bo, bo, bo, bo};
      #pragma unroll
      for (int ks = 0; ks < 4; ks++) {
        half8 av = *(const half8*)&h_s[nidx][(wv * 16 + l15) * SH + ks * 32 + lg * 8];
        oa = __builtin_amdgcn_mfma_f32_16x16x32_f16(av, fout[ks], oa, 0, 0, 0);
      }
      int j = l15;
      #pragma unroll
      for (int r = 0; r < 4; r++) {
        int ag = wv * 16 + lg * 4 + r;
        float mk = mask_s[idx][ag];
        float nv = oa[r];
        float y;
        if (j < 2)      y = nv;
        else if (j < 4) y = 0.01f + 0.2f * sigmf(nv);
        else            y = 0.7f * sigmf(nv);
        if (j < 5) out[((size_t)t * NAG + a0 + ag) * 5 + j] = y * mk;
      }
    }
    if (t + 1 < T_OUT) emb_compute();
    __syncthreads();   // bar2: e_{t+1} visible before next step's MFMAs
  }
}

extern "C" void kernel_launch(void* const* d_in, const int* in_sizes, int n_in,
                              void* d_out, int out_size, void* d_ws, size_t ws_size,
                              hipStream_t stream) {
  const float* obs    = (const float*)d_in[0];
  const float* w_emb  = (const float*)d_in[2];
  const float* b_emb  = (const float*)d_in[3];
  const float* w_ih_e = (const float*)d_in[4];
  const float* b_ih_e = (const float*)d_in[5];
  const float* w_hh_e = (const float*)d_in[6];
  const float* b_hh_e = (const float*)d_in[7];
  const float* w_ih_d = (const float*)d_in[8];
  const float* b_ih_d = (const float*)d_in[9];
  const float* w_hh_d = (const float*)d_in[10];
  const float* b_hh_d = (const float*)d_in[11];
  const float* w_out  = (const float*)d_in[12];
  const float* b_out  = (const float*)d_in[13];
  float* out = (float*)d_out;

  lstm_seq_kernel<<<dim3(250), dim3(512), 0, stream>>>(
      obs, w_emb, b_emb, w_ih_e, b_ih_e, w_hh_e, b_hh_e,
      w_ih_d, b_ih_d, w_hh_d, b_hh_d, w_out, b_out, out);
}